// Round 2
// baseline (634.498 us; speedup 1.0000x reference)
//
#include <hip/hip_runtime.h>
#include <cstdint>
#include <cstddef>

#define E_DIM 1024
#define S_LEN 2048
#define NB 4
#define NH 16
#define F_DIM 4096

typedef __attribute__((ext_vector_type(8))) __bf16 bf16x8;
typedef __attribute__((ext_vector_type(4))) __bf16 bf16x4;
typedef __attribute__((ext_vector_type(4))) float f32x4;
typedef __attribute__((ext_vector_type(16))) float f32x16;

__device__ __forceinline__ f32x4 mfma16(bf16x8 a, bf16x8 b, f32x4 c) {
  return __builtin_amdgcn_mfma_f32_16x16x32_bf16(a, b, c, 0, 0, 0);
}
__device__ __forceinline__ f32x16 mfma32(bf16x8 a, bf16x8 b, f32x16 c) {
  return __builtin_amdgcn_mfma_f32_32x32x16_bf16(a, b, c, 0, 0, 0);
}

// fp32 -> bf16 bits via HW convert (RNE)
__device__ __forceinline__ unsigned short f2bf(float f) {
  __bf16 h = (__bf16)f;
  return __builtin_bit_cast(unsigned short, h);
}

// async global->LDS, 16B per lane. LDS dest must be wave-uniform base + lane*16.
__device__ __forceinline__ void gl_lds16(const void* gptr, void* lptr) {
  __builtin_amdgcn_global_load_lds(
      (const __attribute__((address_space(1))) void*)gptr,
      (__attribute__((address_space(3))) void*)lptr, 16, 0, 0);
}

// ---------------- prep kernels ----------------

__global__ __launch_bounds__(256) void cast_emb_kernel(
    const float4* __restrict__ in, ushort4* __restrict__ out) {
  int i = blockIdx.x * 256 + threadIdx.x;
  float4 v = in[i];
  ushort4 o;
  o.x = f2bf(v.x); o.y = f2bf(v.y); o.z = f2bf(v.z); o.w = f2bf(v.w);
  out[i] = o;
}

// generic: in [batch][R][C] fp32 -> out[(bz*C+c)*R + r] bf16
__global__ __launch_bounds__(256) void transpose_cast_kernel(
    const float* __restrict__ in, unsigned short* __restrict__ out, int R, int C) {
  __shared__ float tile[32][33];
  const int bz = blockIdx.z;
  const float* ip = in + (size_t)bz * R * C;
  const int r0 = blockIdx.y * 32, c0 = blockIdx.x * 32;
  const int tc = threadIdx.x & 31, tr = threadIdx.x >> 5;  // tr 0..7
#pragma unroll
  for (int i = 0; i < 4; ++i)
    tile[tr + i * 8][tc] = ip[(size_t)(r0 + tr + i * 8) * C + (c0 + tc)];
  __syncthreads();
#pragma unroll
  for (int i = 0; i < 4; ++i)
    out[(size_t)(bz * C + c0 + tr + i * 8) * R + (r0 + tc)] = f2bf(tile[tc][tr + i * 8]);
}

// QKV weights: 3 x [16][1024][64] -> one B^T buffer [3072][1024]
__global__ __launch_bounds__(256) void transpose_cast_qkv(
    const float* __restrict__ wq, const float* __restrict__ wk,
    const float* __restrict__ wv, unsigned short* __restrict__ out) {
  __shared__ float tile[32][33];
  const int bz = blockIdx.z;  // 0..47
  const int which = bz >> 4, hz = bz & 15;
  const float* ip =
      (which == 0 ? wq : which == 1 ? wk : wv) + (size_t)hz * 1024 * 64;
  unsigned short* op = out + (size_t)which * 1024 * 1024;
  const int r0 = blockIdx.y * 32, c0 = blockIdx.x * 32;
  const int tc = threadIdx.x & 31, tr = threadIdx.x >> 5;
#pragma unroll
  for (int i = 0; i < 4; ++i)
    tile[tr + i * 8][tc] = ip[(size_t)(r0 + tr + i * 8) * 64 + (c0 + tc)];
  __syncthreads();
#pragma unroll
  for (int i = 0; i < 4; ++i)
    op[(size_t)(hz * 64 + c0 + tr + i * 8) * 1024 + (r0 + tc)] =
        f2bf(tile[tc][tr + i * 8]);
}

// up/gate -> interleave-32 B^T: row = 64*(c>>5) + (c&31) + z*32  (z: 0=up,1=gate)
__global__ __launch_bounds__(256) void transpose_cast_upgate(
    const float* __restrict__ wup, const float* __restrict__ wgate,
    unsigned short* __restrict__ out) {
  __shared__ float tile[32][33];
  const int z = blockIdx.z & 1;
  const float* ip = z ? wgate : wup;
  const int r0 = blockIdx.y * 32, c0 = blockIdx.x * 32;
  const int tc = threadIdx.x & 31, tr = threadIdx.x >> 5;
#pragma unroll
  for (int i = 0; i < 4; ++i)
    tile[tr + i * 8][tc] = ip[(size_t)(r0 + tr + i * 8) * F_DIM + (c0 + tc)];
  __syncthreads();
#pragma unroll
  for (int i = 0; i < 4; ++i) {
    const int c = c0 + tr + i * 8;
    const int row = 64 * (c >> 5) + (c & 31) + z * 32;
    out[(size_t)row * E_DIM + (r0 + tc)] = f2bf(tile[tc][tr + i * 8]);
  }
}

// ------- 128x128 bf16 GEMM, B^T input, BK=64, XOR-swizzled LDS, 32x32x16 MFMA ---
// Wave computes 64x64 as 2x2 of 32x32 tiles. A/B frag: [m=lane&31][k=(lane>>5)*8+j].
// C/D: col = lane&31, row = (reg&3) + 8*(reg>>2) + 4*(lane>>5).
// EPI 0: QKV (+RoPE, scatter to q/k [B,H,S,64] and vT [B,H,64,S]); q pre-scaled 1/8.
// EPI 1/2: fout[idx] = aux[idx] + acc (proj->x, down->out), N must be 1024.
template <int EPI, int KD>
__global__ __launch_bounds__(256) void gemm_bt(
    const unsigned short* __restrict__ A, const unsigned short* __restrict__ Bt,
    const float* __restrict__ aux, const float* __restrict__ cosb,
    const float* __restrict__ sinb,
    unsigned short* __restrict__ qout, unsigned short* __restrict__ kout,
    unsigned short* __restrict__ vtout, float* __restrict__ fout,
    unsigned short* __restrict__ gout) {
  __shared__ unsigned short As[128 * 64];
  __shared__ unsigned short Bs[128 * 64];
  const int t = threadIdx.x;
  const int lane = t & 63, w = t >> 6;
  const int l31 = lane & 31, half = lane >> 5;
  const int wm = (w >> 1) * 64, wn = (w & 1) * 64;
  const int m0 = blockIdx.y * 128, n0 = blockIdx.x * 128;
  // staging: thread t -> LDS row sr, phys chunk (t&7); global chunk = (t&7)^(sr&7)
  const int sr = t >> 3, sc = t & 7;
  const int gcoff = (sc ^ (sr & 7)) * 8;  // shorts
  const unsigned short* ga = A + (size_t)(m0 + sr) * KD + gcoff;
  const unsigned short* gb = Bt + (size_t)(n0 + sr) * KD + gcoff;
  unsigned short* lA = &As[sr * 64 + sc * 8];
  unsigned short* lB = &Bs[sr * 64 + sc * 8];
  const int xh = lane & 7;  // fragment-read swizzle key (= row&7 for frag rows)
  f32x16 acc[2][2] = {};
  for (int k0 = 0; k0 < KD; k0 += 64) {
    __syncthreads();
#pragma unroll
    for (int i = 0; i < 4; ++i) {
      gl_lds16(ga + (size_t)(i * 32) * KD + k0, lA + i * 32 * 64);
      gl_lds16(gb + (size_t)(i * 32) * KD + k0, lB + i * 32 * 64);
    }
    __syncthreads();
#pragma unroll
    for (int ksl = 0; ksl < 4; ++ksl) {
      const int cp = ((ksl * 2 + half) ^ xh) * 8;
      bf16x8 af[2], bfr[2];
#pragma unroll
      for (int mi = 0; mi < 2; ++mi)
        af[mi] = *reinterpret_cast<const bf16x8*>(&As[(wm + mi * 32 + l31) * 64 + cp]);
#pragma unroll
      for (int ni = 0; ni < 2; ++ni)
        bfr[ni] = *reinterpret_cast<const bf16x8*>(&Bs[(wn + ni * 32 + l31) * 64 + cp]);
#pragma unroll
      for (int mi = 0; mi < 2; ++mi)
#pragma unroll
        for (int ni = 0; ni < 2; ++ni)
          acc[mi][ni] = mfma32(af[mi], bfr[ni], acc[mi][ni]);
    }
  }
  // epilogues
  if (EPI == 0) {
#pragma unroll
    for (int mi = 0; mi < 2; ++mi)
#pragma unroll
      for (int ni = 0; ni < 2; ++ni) {
        const int n = n0 + wn + ni * 32 + l31;
        const int seg = n >> 10, rest = n & 1023, hh = rest >> 6, kk = rest & 63;
#pragma unroll
        for (int reg = 0; reg < 16; ++reg) {
          const int m = m0 + wm + mi * 32 + (reg & 3) + 8 * (reg >> 2) + 4 * half;
          const int b = m >> 11, s = m & 2047;
          const float v = acc[mi][ni][reg];
          if (seg == 2) {
            vtout[(((size_t)(b * NH + hh)) * 64 + kk) * S_LEN + s] = f2bf(v);
          } else {
            const float sw = acc[mi][ni ^ 1][reg];  // col kk^32: same lane, other ni
            const float cv = cosb[s * 64 + kk], sv = sinb[s * 64 + kk];
            const float scl = (seg == 0) ? 0.125f : 1.0f;  // fold 1/sqrt(K) into q
            unsigned short* dst = (seg == 0) ? qout : kout;
            dst[(((size_t)(b * NH + hh)) * S_LEN + s) * 64 + kk] =
                f2bf((cv * v + sv * sw) * scl);
          }
        }
      }
  } else {
#pragma unroll
    for (int mi = 0; mi < 2; ++mi)
#pragma unroll
      for (int ni = 0; ni < 2; ++ni) {
        const int n = n0 + wn + ni * 32 + l31;
#pragma unroll
        for (int reg = 0; reg < 16; ++reg) {
          const int m = m0 + wm + mi * 32 + (reg & 3) + 8 * (reg >> 2) + 4 * half;
          const size_t idx = (size_t)m * 1024 + n;
          fout[idx] = aux[idx] + acc[mi][ni][reg];
        }
      }
  }
}

// ---------------- 256x256 4-phase pipelined GEMM v2 (up/gate fused) ----------------
// BM=BN=256, BK=64, 512 thr = 8 waves (2M x 4N), per-wave 128x64 = 4x2 of 32x32,
// 32x32x16 MFMA (2495 TF pipe vs 2075 for 16x16).
// LDS: 8 regions x 16KB (2 buffers x {B_h0, A_h0, B_h1, A_h1}); region = 256 rows
// x 32 shorts (one 32-wide k-half). Swizzle: phys chunk = logical ^ s(row),
// s(r) = (r ^ (r>>2)) & 3  -> 2-way floor on b128 reads (the r&3-only variant was
// a 4-way conflict: rows r,r+4,r+8,r+12 in a quarter-wave shared a chunk).
// Staging: global_load_lds 16B/lane, linear LDS dest, inverse-swizzled source.
// Phase p=0..3 of tile t: [vmcnt(4) at P0/P2 only]; barrier; 6 ds_read_b128
// (a[4],b[2] for k-step p); issue 1 pair for tile t+1; 8 x mfma32 (setprio-wrapped).
// 4 pairs (8 loads) in flight across every barrier; tail drains via vmcnt(0) at P2.
#define FENCE() asm volatile("" ::: "memory")
#define BARX()                        \
  do {                                \
    FENCE();                          \
    __builtin_amdgcn_s_barrier();     \
    FENCE();                          \
  } while (0)

__global__ __launch_bounds__(512, 2) void gemm256_upgate(
    const unsigned short* __restrict__ A, const unsigned short* __restrict__ Bt,
    unsigned short* __restrict__ gout) {
  constexpr int KD = 1024;
  constexpr int NT = KD / 64;  // 16 K-tiles
  __shared__ unsigned short L[8 * 8192];  // 128 KiB
  const int tid = threadIdx.x;
  const int lane = tid & 63, w = tid >> 6;
  const int l31 = lane & 31, half = lane >> 5;
  const int wm = (w >> 2) * 128, wn = (w & 3) * 64;
  const int m0 = blockIdx.y * 256, n0 = blockIdx.x * 256;
  // staging map: thread -> row r = tid>>2 (+128 for 2nd load), phys chunk tid&3,
  // source global chunk = (tid&3) ^ s(r)   (s unchanged by +128)
  const int r = tid >> 2;
  const int csrc = ((tid & 3) ^ ((r ^ (r >> 2)) & 3)) * 8;  // shorts
  const unsigned short* gA = A + (size_t)(m0 + r) * KD + csrc;
  const unsigned short* gB = Bt + (size_t)(n0 + r) * KD + csrc;
  const int ldst = tid * 8;  // shorts: linear 16B/lane dest within region
  const int sA = (l31 ^ (l31 >> 2)) & 3;  // read swizzle key (= s(row) for frag rows)

  f32x16 acc[4][2] = {};
  bf16x8 a[4], b[2];

#define STG(ridx, gp, koff)                                                    \
  do {                                                                         \
    gl_lds16((gp) + (koff), &L[(ridx) * 8192 + ldst]);                         \
    gl_lds16((gp) + (koff) + (size_t)128 * KD,                                 \
             &L[(ridx) * 8192 + 4096 + ldst]);                                 \
  } while (0)

#define RD(hh, kl, bufi)                                                       \
  do {                                                                         \
    const int xo = ((((kl) * 2 + half) ^ sA)) * 8;                             \
    const int ra = ((bufi) * 4 + 1 + 2 * (hh)) * 8192;                         \
    const int rb = ((bufi) * 4 + 2 * (hh)) * 8192;                             \
    _Pragma("unroll") for (int mi = 0; mi < 4; ++mi)                           \
        a[mi] = *reinterpret_cast<const bf16x8*>(                              \
            &L[ra + (wm + mi * 32 + l31) * 32 + xo]);                          \
    _Pragma("unroll") for (int ni = 0; ni < 2; ++ni)                           \
        b[ni] = *reinterpret_cast<const bf16x8*>(                              \
            &L[rb + (wn + ni * 32 + l31) * 32 + xo]);                          \
  } while (0)

#define MFMA8()                                                                \
  do {                                                                         \
    __builtin_amdgcn_s_setprio(1);                                             \
    _Pragma("unroll") for (int mi = 0; mi < 4; ++mi)                           \
        _Pragma("unroll") for (int ni = 0; ni < 2; ++ni)                       \
            acc[mi][ni] = mfma32(a[mi], b[ni], acc[mi][ni]);                   \
    __builtin_amdgcn_s_setprio(0);                                             \
  } while (0)

  // prologue: tile 0's 4 pairs into buffer 0 (issue order pinned for vmcnt math)
  STG(0, gB, 0); FENCE();
  STG(1, gA, 0); FENCE();
  STG(2, gB, 32); FENCE();
  STG(3, gA, 32); FENCE();

  int buf = 0;
  for (int t = 0; t < NT; ++t, buf ^= 1) {
    const int nx = buf ^ 1;
    const bool pre = (t + 1 < NT);
    const int ko = (t + 1) * 64;
    // ---- P0: k-step 0 (pairs B_h0, A_h0 of tile t) ----
    asm volatile("s_waitcnt vmcnt(4)" ::: "memory");  // B_h0(t), A_h0(t) landed
    BARX();
    RD(0, 0, buf);
    if (pre) STG(nx * 4 + 0, gB, ko);  // B_h0(t+1)
    MFMA8();
    // ---- P1: k-step 1 ----
    BARX();
    RD(0, 1, buf);
    if (pre) STG(nx * 4 + 1, gA, ko);  // A_h0(t+1)
    MFMA8();
    // ---- P2: k-step 2 (pairs B_h1, A_h1) ----
    if (pre) {
      asm volatile("s_waitcnt vmcnt(4)" ::: "memory");  // B_h1(t), A_h1(t) landed
    } else {
      asm volatile("s_waitcnt vmcnt(0)" ::: "memory");  // tail drain
    }
    BARX();
    RD(1, 0, buf);
    if (pre) STG(nx * 4 + 2, gB, ko + 32);  // B_h1(t+1)
    MFMA8();
    // ---- P3: k-step 3 ----
    BARX();
    RD(1, 1, buf);
    if (pre) STG(nx * 4 + 3, gA, ko + 32);  // A_h1(t+1)
    MFMA8();
  }
  // ---- epilogue: gout[m][col] = u * elu(g); ni 0 = up block, ni 1 = gate ----
  const int colb = ((n0 + wn) >> 1) + l31;
#pragma unroll
  for (int mi = 0; mi < 4; ++mi)
#pragma unroll
    for (int reg = 0; reg < 16; ++reg) {
      const int m = m0 + wm + mi * 32 + (reg & 3) + 8 * (reg >> 2) + 4 * half;
      const float uu = acc[mi][0][reg], gg = acc[mi][1][reg];
      const float e = gg > 0.f ? gg : (__expf(gg) - 1.f);
      gout[(size_t)m * F_DIM + colb] = f2bf(uu * e);
    }
#undef STG
#undef RD
#undef MFMA8
}

// ---------------- flash attention (causal), BQ=128, BKV=64 ----------------
// q pre-scaled by 1/8; fixed-shift softmax: p = exp(s - 8) (exact, scores bounded).
// K/V tiles XOR-swizzled (conflict-free frag reads). LPT: qt descending.
#define PS_STRIDE 68  // 136B rows: 8B-aligned, quad bank offset 8 -> conflict-free writes
__global__ __launch_bounds__(256) void flash_attn(
    const unsigned short* __restrict__ qb, const unsigned short* __restrict__ kb,
    const unsigned short* __restrict__ vtb, unsigned short* __restrict__ attn) {
  __shared__ unsigned short Ks[64 * 64];
  __shared__ unsigned short Vts[64 * 64];  // [d][t_local]
  __shared__ unsigned short Ps[128 * PS_STRIDE];
  const int t = threadIdx.x, lane = t & 63, w = t >> 6;
  const int quad = lane >> 4, l15 = lane & 15;
  const int qt = 15 - blockIdx.y;  // LPT: longest blocks dispatch first
  const int bh = blockIdx.x;
  const int b = bh >> 4, hh = bh & 15;
  const unsigned short* qg = qb + (size_t)bh * S_LEN * 64;
  const unsigned short* kg = kb + (size_t)bh * S_LEN * 64;
  const unsigned short* vg = vtb + (size_t)bh * 64 * S_LEN;
  // Q fragments: iteration-invariant, load straight to registers (A-layout)
  bf16x8 aq[2][2];
#pragma unroll
  for (int mi = 0; mi < 2; ++mi)
#pragma unroll
    for (int ks = 0; ks < 2; ++ks)
      aq[mi][ks] = *reinterpret_cast<const bf16x8*>(
          qg + (size_t)(qt * 128 + w * 32 + mi * 16 + l15) * 64 + ks * 32 + quad * 8);
  f32x4 o[2][4] = {};
  float lpart[2][4] = {};  // per-lane partial softmax denominators
  const int srk = t >> 3, sck = t & 7;
  const int gck = ((sck ^ (srk & 7)) * 8);  // swizzled global chunk (shorts)
  const int xh = l15 & 7;
  const int ktmax = 2 * qt + 1;
  for (int kt = 0; kt <= ktmax; ++kt) {
    __syncthreads();
#pragma unroll
    for (int i = 0; i < 2; ++i) {
      gl_lds16(kg + (size_t)(kt * 64 + srk + i * 32) * 64 + gck,
               &Ks[(srk + i * 32) * 64 + sck * 8]);
      gl_lds16(vg + (size_t)(srk + i * 32) * S_LEN + kt * 64 + gck,
               &Vts[(srk + i * 32) * 64 + sck * 8]);
    }
    __syncthreads();
    // S = q.k/8 - 8 (shift folded into accumulator init)
    f32x4 sacc[2][4];
#pragma unroll
    for (int mi = 0; mi < 2; ++mi)
#pragma unroll
      for (int nt = 0; nt < 4; ++nt) sacc[mi][nt] = (f32x4){-8.f, -8.f, -8.f, -8.f};
#pragma unroll
    for (int nt = 0; nt < 4; ++nt) {
      bf16x8 b0 = *reinterpret_cast<const bf16x8*>(
          &Ks[(nt * 16 + l15) * 64 + ((quad ^ xh) * 8)]);
      bf16x8 b1 = *reinterpret_cast<const bf16x8*>(
          &Ks[(nt * 16 + l15) * 64 + (((4 + quad) ^ xh) * 8)]);
#pragma unroll
      for (int mi = 0; mi < 2; ++mi) {
        sacc[mi][nt] = mfma16(aq[mi][0], b0, sacc[mi][nt]);
        sacc[mi][nt] = mfma16(aq[mi][1], b1, sacc[mi][nt]);
      }
    }
    if (kt >= 2 * qt) {  // diagonal tiles: causal mask
#pragma unroll
      for (int mi = 0; mi < 2; ++mi)
#pragma unroll
        for (int nt = 0; nt < 4; ++nt)
#pragma unroll
          for (int rg = 0; rg < 4; ++rg) {
            const int row = qt * 128 + w * 32 + mi * 16 + quad * 4 + rg;
            const int col = kt * 64 + nt * 16 + l15;
            if (col > row) sacc[mi][nt][rg] = -1e9f;
          }
    }
    // p = exp(s-8); accumulate per-lane l; write P to LDS (bf16, padded rows)
#pragma unroll
    for (int mi = 0; mi < 2; ++mi)
#pragma unroll
      for (int nt = 0; nt < 4; ++nt)
#pragma unroll
        for (int rg = 0; rg < 4; ++rg) {
          const float p = __expf(sacc[mi][nt][rg]);
          lpart[mi][rg] += p;
          Ps[(w * 32 + mi * 16 + quad * 4 + rg) * PS_STRIDE + nt * 16 + l15] = f2bf(p);
        }
    // PV: same-wave LDS round-trip (rows w*32..w*32+31 only, no barrier needed)
#pragma unroll
    for (int ks = 0; ks < 2; ++ks) {
      bf16x8 ap[2];
#pragma unroll
      for (int mi = 0; mi < 2; ++mi) {
        const unsigned short* pp =
            &Ps[(w * 32 + mi * 16 + l15) * PS_STRIDE + ks * 32 + quad * 8];
        bf16x4 lo = *reinterpret_cast<const bf16x4*>(pp);
        bf16x4 hi = *reinterpret_cast<const bf16x4*>(pp + 4);
        ap[mi] = __builtin_shufflevector(lo, hi, 0, 1, 2, 3, 4, 5, 6, 7);
      }
#pragma unroll
      for (int vt = 0; vt < 4; ++vt) {
        bf16x8 bv = *reinterpret_cast<const bf16x8*>(
            &Vts[(vt * 16 + l15) * 64 + (((ks * 4 + quad) ^ xh) * 8)]);
#pragma unroll
        for (int mi = 0; mi < 2; ++mi) o[mi][vt] = mfma16(ap[mi], bv, o[mi][vt]);
      }
    }
  }
  // final denominator reduce across the 16 col-lanes of each row
  float linv[2][4];
#pragma unroll
  for (int mi = 0; mi < 2; ++mi)
#pragma unroll
    for (int rg = 0; rg < 4; ++rg) {
      float rs = lpart[mi][rg];
#pragma unroll
      for (int d = 1; d < 16; d <<= 1) rs += __shfl_xor(rs, d);
      linv[mi][rg] = 1.0f / rs;
    }
#pragma unroll
  for (int mi = 0; mi < 2; ++mi)
#pragma unroll
    for (int vt = 0; vt < 4; ++vt)
#pragma unroll
      for (int rg = 0; rg < 4; ++rg) {
        const int row = w * 32 + mi * 16 + quad * 4 + rg;
        const int s = qt * 128 + row;
        const float ov = o[mi][vt][rg] * linv[mi][rg];
        attn[((size_t)(b * S_LEN + s)) * E_DIM + hh * 64 + vt * 16 + l15] = f2bf(ov);
      }
}

// ---------------- rmsnorm: h = x * rsqrt(mean(x^2)+eps) * w  (bf16 out) ----------------
__global__ __launch_bounds__(256) void rmsnorm_kernel(
    const float* __restrict__ x, const float* __restrict__ wgt,
    unsigned short* __restrict__ hout) {
  const int row = blockIdx.x;
  const int t = threadIdx.x;
  const float4 v = reinterpret_cast<const float4*>(x + (size_t)row * E_DIM)[t];
  float ss = v.x * v.x + v.y * v.y + v.z * v.z + v.w * v.w;
#pragma unroll
  for (int d = 1; d < 64; d <<= 1) ss += __shfl_xor(ss, d);
  __shared__ float red[4];
  if ((t & 63) == 0) red[t >> 6] = ss;
  __syncthreads();
  const float tot = red[0] + red[1] + red[2] + red[3];
  const float sc = rsqrtf(tot * (1.f / 1024.f) + 1.1920929e-07f);
  const float4 g = reinterpret_cast<const float4*>(wgt)[t];
  ushort4 ov;
  ov.x = f2bf(v.x * sc * g.x);
  ov.y = f2bf(v.y * sc * g.y);
  ov.z = f2bf(v.z * sc * g.z);
  ov.w = f2bf(v.w * sc * g.w);
  reinterpret_cast<ushort4*>(hout + (size_t)row * E_DIM)[t] = ov;
}

// ---------------- host ----------------
extern "C" void kernel_launch(void* const* d_in, const int* in_sizes, int n_in,
                              void* d_out, int out_size, void* d_ws, size_t ws_size,
                              hipStream_t stream) {
  (void)in_sizes; (void)n_in; (void)out_size; (void)ws_size;
  const float* emb = (const float*)d_in[0];
  const float* cosb = (const float*)d_in[2];
  const float* sinb = (const float*)d_in[3];
  const float* wq = (const float*)d_in[4];
  const float* wk = (const float*)d_in[5];
  const float* wv = (const float*)d_in[6];
  const float* wproj = (const float*)d_in[7];
  const float* mlpw = (const float*)d_in[9];
  const float* wup = (const float*)d_in[10];
  const float* wgate = (const float*)d_in[11];
  const float* wdown = (const float*)d_in[12];
  float* out = (float*)d_out;
  char* ws = (char*)d_ws;
  // layout (bytes): weights 32MiB | shared67 (emb_bf16,q,k,vt | aliased later by g) | attn | x | h
  unsigned short* wqkv_t = (unsigned short*)(ws + 0);
  unsigned short* wproj_t = (unsigned short*)(ws + 6291456);
  unsigned short* wupgate_t = (unsigned short*)(ws + 8388608);  // interleave-32 U/G, 8192x1024
  unsigned short* wdown_t = (unsigned short*)(ws + 25165824);
  unsigned short* embb = (unsigned short*)(ws + 33554432);
  unsigned short* qbuf = (unsigned short*)(ws + 50331648);
  unsigned short* kbuf = (unsigned short*)(ws + 67108864);
  unsigned short* vtbuf = (unsigned short*)(ws + 83886080);
  unsigned short* gbuf = (unsigned short*)(ws + 33554432);  // aliases embb..vtbuf (dead by then)
  unsigned short* attnb = (unsigned short*)(ws + 100663296);
  float* xbuf = (float*)(ws + 117440512);
  unsigned short* hbuf = (unsigned short*)(ws + 150994944);

  dim3 blk(256);
  // prep: casts + transposes to B^T layouts
  cast_emb_kernel<<<8192, blk, 0, stream>>>((const float4*)emb, (ushort4*)embb);
  transpose_cast_qkv<<<dim3(2, 32, 48), blk, 0, stream>>>(wq, wk, wv, wqkv_t);
  transpose_cast_kernel<<<dim3(32, 32, 1), blk, 0, stream>>>(wproj, wproj_t, 1024, 1024);
  transpose_cast_upgate<<<dim3(128, 32, 2), blk, 0, stream>>>(wup, wgate, wupgate_t);
  transpose_cast_kernel<<<dim3(32, 128, 1), blk, 0, stream>>>(wdown, wdown_t, 4096, 1024);
  // QKV + RoPE (q pre-scaled by 1/8)
  gemm_bt<0, 1024><<<dim3(24, 64), blk, 0, stream>>>(
      embb, wqkv_t, nullptr, cosb, sinb, qbuf, kbuf, vtbuf, nullptr, nullptr);
  // causal flash attention (LPT order)
  flash_attn<<<dim3(64, 16), blk, 0, stream>>>(qbuf, kbuf, vtbuf, attnb);
  // proj + residual -> x (fp32)
  gemm_bt<1, 1024><<<dim3(8, 64), blk, 0, stream>>>(
      attnb, wproj_t, emb, nullptr, nullptr, nullptr, nullptr, nullptr, xbuf, nullptr);
  // rmsnorm -> h (bf16)
  rmsnorm_kernel<<<8192, blk, 0, stream>>>(xbuf, mlpw, hbuf);
  // fused up/gate (interleave-32 B, 256^2 4-phase pipelined, mfma32) -> g (bf16)
  gemm256_upgate<<<dim3(32, 32), dim3(512), 0, stream>>>(hbuf, wupgate_t, gbuf);
  // down + residual -> out (fp32)
  gemm_bt<2, 4096><<<dim3(8, 64), blk, 0, stream>>>(
      gbuf, wdown_t, xbuf, nullptr, nullptr, nullptr, nullptr, nullptr, out, nullptr);
}

// Round 3
// 594.852 us; speedup vs baseline: 1.0666x; 1.0666x over previous
//
#include <hip/hip_runtime.h>
#include <cstdint>
#include <cstddef>

#define E_DIM 1024
#define S_LEN 2048
#define NB 4
#define NH 16
#define F_DIM 4096

typedef __attribute__((ext_vector_type(8))) __bf16 bf16x8;
typedef __attribute__((ext_vector_type(4))) __bf16 bf16x4;
typedef __attribute__((ext_vector_type(4))) float f32x4;
typedef __attribute__((ext_vector_type(16))) float f32x16;

__device__ __forceinline__ f32x4 mfma16(bf16x8 a, bf16x8 b, f32x4 c) {
  return __builtin_amdgcn_mfma_f32_16x16x32_bf16(a, b, c, 0, 0, 0);
}
__device__ __forceinline__ f32x16 mfma32(bf16x8 a, bf16x8 b, f32x16 c) {
  return __builtin_amdgcn_mfma_f32_32x32x16_bf16(a, b, c, 0, 0, 0);
}

// fp32 -> bf16 bits via HW convert (RNE)
__device__ __forceinline__ unsigned short f2bf(float f) {
  __bf16 h = (__bf16)f;
  return __builtin_bit_cast(unsigned short, h);
}

// async global->LDS, 16B per lane. LDS dest must be wave-uniform base + lane*16.
__device__ __forceinline__ void gl_lds16(const void* gptr, void* lptr) {
  __builtin_amdgcn_global_load_lds(
      (const __attribute__((address_space(1))) void*)gptr,
      (__attribute__((address_space(3))) void*)lptr, 16, 0, 0);
}

// ---------------- prep kernels ----------------

__global__ __launch_bounds__(256) void cast_emb_kernel(
    const float4* __restrict__ in, ushort4* __restrict__ out) {
  int i = blockIdx.x * 256 + threadIdx.x;
  float4 v = in[i];
  ushort4 o;
  o.x = f2bf(v.x); o.y = f2bf(v.y); o.z = f2bf(v.z); o.w = f2bf(v.w);
  out[i] = o;
}

// generic: in [batch][R][C] fp32 -> out[(bz*C+c)*R + r] bf16
__global__ __launch_bounds__(256) void transpose_cast_kernel(
    const float* __restrict__ in, unsigned short* __restrict__ out, int R, int C) {
  __shared__ float tile[32][33];
  const int bz = blockIdx.z;
  const float* ip = in + (size_t)bz * R * C;
  const int r0 = blockIdx.y * 32, c0 = blockIdx.x * 32;
  const int tc = threadIdx.x & 31, tr = threadIdx.x >> 5;  // tr 0..7
#pragma unroll
  for (int i = 0; i < 4; ++i)
    tile[tr + i * 8][tc] = ip[(size_t)(r0 + tr + i * 8) * C + (c0 + tc)];
  __syncthreads();
#pragma unroll
  for (int i = 0; i < 4; ++i)
    out[(size_t)(bz * C + c0 + tr + i * 8) * R + (r0 + tc)] = f2bf(tile[tc][tr + i * 8]);
}

// QKV weights: 3 x [16][1024][64] -> one B^T buffer [3072][1024]
__global__ __launch_bounds__(256) void transpose_cast_qkv(
    const float* __restrict__ wq, const float* __restrict__ wk,
    const float* __restrict__ wv, unsigned short* __restrict__ out) {
  __shared__ float tile[32][33];
  const int bz = blockIdx.z;  // 0..47
  const int which = bz >> 4, hz = bz & 15;
  const float* ip =
      (which == 0 ? wq : which == 1 ? wk : wv) + (size_t)hz * 1024 * 64;
  unsigned short* op = out + (size_t)which * 1024 * 1024;
  const int r0 = blockIdx.y * 32, c0 = blockIdx.x * 32;
  const int tc = threadIdx.x & 31, tr = threadIdx.x >> 5;
#pragma unroll
  for (int i = 0; i < 4; ++i)
    tile[tr + i * 8][tc] = ip[(size_t)(r0 + tr + i * 8) * 64 + (c0 + tc)];
  __syncthreads();
#pragma unroll
  for (int i = 0; i < 4; ++i)
    op[(size_t)(hz * 64 + c0 + tr + i * 8) * 1024 + (r0 + tc)] =
        f2bf(tile[tc][tr + i * 8]);
}

// up/gate -> interleave-32 B^T: row = 64*(c>>5) + (c&31) + z*32  (z: 0=up,1=gate)
__global__ __launch_bounds__(256) void transpose_cast_upgate(
    const float* __restrict__ wup, const float* __restrict__ wgate,
    unsigned short* __restrict__ out) {
  __shared__ float tile[32][33];
  const int z = blockIdx.z & 1;
  const float* ip = z ? wgate : wup;
  const int r0 = blockIdx.y * 32, c0 = blockIdx.x * 32;
  const int tc = threadIdx.x & 31, tr = threadIdx.x >> 5;
#pragma unroll
  for (int i = 0; i < 4; ++i)
    tile[tr + i * 8][tc] = ip[(size_t)(r0 + tr + i * 8) * F_DIM + (c0 + tc)];
  __syncthreads();
#pragma unroll
  for (int i = 0; i < 4; ++i) {
    const int c = c0 + tr + i * 8;
    const int row = 64 * (c >> 5) + (c & 31) + z * 32;
    out[(size_t)row * E_DIM + (r0 + tc)] = f2bf(tile[tc][tr + i * 8]);
  }
}

// ------- 128x128 bf16 GEMM, B^T input, BK=64, XOR-swizzled LDS, 32x32x16 MFMA ---
// Wave computes 64x64 as 2x2 of 32x32 tiles. A/B frag: [m=lane&31][k=(lane>>5)*8+j].
// C/D: col = lane&31, row = (reg&3) + 8*(reg>>2) + 4*(lane>>5).
// EPI 0: QKV (+RoPE, scatter to q/k [B,H,S,64] and vT [B,H,64,S]); q pre-scaled 1/8.
// EPI 1: fout[idx] = aux[idx] + acc (proj->x), N must be 1024.
template <int EPI, int KD>
__global__ __launch_bounds__(256) void gemm_bt(
    const unsigned short* __restrict__ A, const unsigned short* __restrict__ Bt,
    const float* __restrict__ aux, const float* __restrict__ cosb,
    const float* __restrict__ sinb,
    unsigned short* __restrict__ qout, unsigned short* __restrict__ kout,
    unsigned short* __restrict__ vtout, float* __restrict__ fout,
    unsigned short* __restrict__ gout) {
  __shared__ unsigned short As[128 * 64];
  __shared__ unsigned short Bs[128 * 64];
  const int t = threadIdx.x;
  const int lane = t & 63, w = t >> 6;
  const int l31 = lane & 31, half = lane >> 5;
  const int wm = (w >> 1) * 64, wn = (w & 1) * 64;
  const int m0 = blockIdx.y * 128, n0 = blockIdx.x * 128;
  // staging: thread t -> LDS row sr, phys chunk (t&7); global chunk = (t&7)^(sr&7)
  const int sr = t >> 3, sc = t & 7;
  const int gcoff = (sc ^ (sr & 7)) * 8;  // shorts
  const unsigned short* ga = A + (size_t)(m0 + sr) * KD + gcoff;
  const unsigned short* gb = Bt + (size_t)(n0 + sr) * KD + gcoff;
  unsigned short* lA = &As[sr * 64 + sc * 8];
  unsigned short* lB = &Bs[sr * 64 + sc * 8];
  const int xh = lane & 7;  // fragment-read swizzle key (= row&7 for frag rows)
  f32x16 acc[2][2] = {};
  for (int k0 = 0; k0 < KD; k0 += 64) {
    __syncthreads();
#pragma unroll
    for (int i = 0; i < 4; ++i) {
      gl_lds16(ga + (size_t)(i * 32) * KD + k0, lA + i * 32 * 64);
      gl_lds16(gb + (size_t)(i * 32) * KD + k0, lB + i * 32 * 64);
    }
    __syncthreads();
#pragma unroll
    for (int ksl = 0; ksl < 4; ++ksl) {
      const int cp = ((ksl * 2 + half) ^ xh) * 8;
      bf16x8 af[2], bfr[2];
#pragma unroll
      for (int mi = 0; mi < 2; ++mi)
        af[mi] = *reinterpret_cast<const bf16x8*>(&As[(wm + mi * 32 + l31) * 64 + cp]);
#pragma unroll
      for (int ni = 0; ni < 2; ++ni)
        bfr[ni] = *reinterpret_cast<const bf16x8*>(&Bs[(wn + ni * 32 + l31) * 64 + cp]);
#pragma unroll
      for (int mi = 0; mi < 2; ++mi)
#pragma unroll
        for (int ni = 0; ni < 2; ++ni)
          acc[mi][ni] = mfma32(af[mi], bfr[ni], acc[mi][ni]);
    }
  }
  // epilogues
  if (EPI == 0) {
#pragma unroll
    for (int mi = 0; mi < 2; ++mi)
#pragma unroll
      for (int ni = 0; ni < 2; ++ni) {
        const int n = n0 + wn + ni * 32 + l31;
        const int seg = n >> 10, rest = n & 1023, hh = rest >> 6, kk = rest & 63;
#pragma unroll
        for (int reg = 0; reg < 16; ++reg) {
          const int m = m0 + wm + mi * 32 + (reg & 3) + 8 * (reg >> 2) + 4 * half;
          const int b = m >> 11, s = m & 2047;
          const float v = acc[mi][ni][reg];
          if (seg == 2) {
            vtout[(((size_t)(b * NH + hh)) * 64 + kk) * S_LEN + s] = f2bf(v);
          } else {
            const float sw = acc[mi][ni ^ 1][reg];  // col kk^32: same lane, other ni
            const float cv = cosb[s * 64 + kk], sv = sinb[s * 64 + kk];
            const float scl = (seg == 0) ? 0.125f : 1.0f;  // fold 1/sqrt(K) into q
            unsigned short* dst = (seg == 0) ? qout : kout;
            dst[(((size_t)(b * NH + hh)) * S_LEN + s) * 64 + kk] =
                f2bf((cv * v + sv * sw) * scl);
          }
        }
      }
  } else {
#pragma unroll
    for (int mi = 0; mi < 2; ++mi)
#pragma unroll
      for (int ni = 0; ni < 2; ++ni) {
        const int n = n0 + wn + ni * 32 + l31;
#pragma unroll
        for (int reg = 0; reg < 16; ++reg) {
          const int m = m0 + wm + mi * 32 + (reg & 3) + 8 * (reg >> 2) + 4 * half;
          const size_t idx = (size_t)m * 1024 + n;
          fout[idx] = aux[idx] + acc[mi][ni][reg];
        }
      }
  }
}

// ---------------- 256x256 4-phase pipelined GEMM v2 (up/gate fused) ----------------
// BM=BN=256, BK=64, 512 thr = 8 waves (2M x 4N), per-wave 128x64 = 4x2 of 32x32,
// 32x32x16 MFMA. LDS: 8 regions x 16KB (2 buffers x {B_h0, A_h0, B_h1, A_h1});
// region = 256 rows x 32 shorts. Swizzle: phys chunk = logical ^ s(row),
// s(r) = (r ^ (r>>2)) & 3 (2-way floor on b128 reads).
#define FENCE() asm volatile("" ::: "memory")
#define BARX()                        \
  do {                                \
    FENCE();                          \
    __builtin_amdgcn_s_barrier();     \
    FENCE();                          \
  } while (0)
#define VMW_(n) asm volatile("s_waitcnt vmcnt(" #n ")" ::: "memory")
#define VMW(n) VMW_(n)

__global__ __launch_bounds__(512, 2) void gemm256_upgate(
    const unsigned short* __restrict__ A, const unsigned short* __restrict__ Bt,
    unsigned short* __restrict__ gout) {
  constexpr int KD = 1024;
  constexpr int NT = KD / 64;  // 16 K-tiles
  __shared__ unsigned short L[8 * 8192];  // 128 KiB
  const int tid = threadIdx.x;
  const int lane = tid & 63, w = tid >> 6;
  const int l31 = lane & 31, half = lane >> 5;
  const int wm = (w >> 2) * 128, wn = (w & 3) * 64;
  const int m0 = blockIdx.y * 256, n0 = blockIdx.x * 256;
  const int r = tid >> 2;
  const int csrc = ((tid & 3) ^ ((r ^ (r >> 2)) & 3)) * 8;  // shorts
  const unsigned short* gA = A + (size_t)(m0 + r) * KD + csrc;
  const unsigned short* gB = Bt + (size_t)(n0 + r) * KD + csrc;
  const int ldst = tid * 8;  // shorts: linear 16B/lane dest within region
  const int sA = (l31 ^ (l31 >> 2)) & 3;  // read swizzle key (= s(row) for frag rows)

  f32x16 acc[4][2] = {};
  bf16x8 a[4], b[2];

#define STG(ridx, gp, koff)                                                    \
  do {                                                                         \
    gl_lds16((gp) + (koff), &L[(ridx) * 8192 + ldst]);                         \
    gl_lds16((gp) + (koff) + (size_t)128 * KD,                                 \
             &L[(ridx) * 8192 + 4096 + ldst]);                                 \
  } while (0)

#define RD(hh, kl, bufi)                                                       \
  do {                                                                         \
    const int xo = ((((kl) * 2 + half) ^ sA)) * 8;                             \
    const int ra = ((bufi) * 4 + 1 + 2 * (hh)) * 8192;                         \
    const int rb = ((bufi) * 4 + 2 * (hh)) * 8192;                             \
    _Pragma("unroll") for (int mi = 0; mi < 4; ++mi)                           \
        a[mi] = *reinterpret_cast<const bf16x8*>(                              \
            &L[ra + (wm + mi * 32 + l31) * 32 + xo]);                          \
    _Pragma("unroll") for (int ni = 0; ni < 2; ++ni)                           \
        b[ni] = *reinterpret_cast<const bf16x8*>(                              \
            &L[rb + (wn + ni * 32 + l31) * 32 + xo]);                          \
  } while (0)

#define MFMA8()                                                                \
  do {                                                                         \
    __builtin_amdgcn_s_setprio(1);                                             \
    _Pragma("unroll") for (int mi = 0; mi < 4; ++mi)                           \
        _Pragma("unroll") for (int ni = 0; ni < 2; ++ni)                       \
            acc[mi][ni] = mfma32(a[mi], b[ni], acc[mi][ni]);                   \
    __builtin_amdgcn_s_setprio(0);                                             \
  } while (0)

  // prologue: tile 0's 4 pairs into buffer 0 (issue order pinned for vmcnt math)
  STG(0, gB, 0); FENCE();
  STG(1, gA, 0); FENCE();
  STG(2, gB, 32); FENCE();
  STG(3, gA, 32); FENCE();

  int buf = 0;
  for (int t = 0; t < NT; ++t, buf ^= 1) {
    const int nx = buf ^ 1;
    const bool pre = (t + 1 < NT);
    const int ko = (t + 1) * 64;
    // ---- P0: k-step 0 (pairs B_h0, A_h0 of tile t) ----
    VMW(4);
    BARX();
    RD(0, 0, buf);
    if (pre) STG(nx * 4 + 0, gB, ko);  // B_h0(t+1)
    MFMA8();
    // ---- P1: k-step 1 ----
    BARX();
    RD(0, 1, buf);
    if (pre) STG(nx * 4 + 1, gA, ko);  // A_h0(t+1)
    MFMA8();
    // ---- P2: k-step 2 (pairs B_h1, A_h1) ----
    if (pre) {
      VMW(4);
    } else {
      VMW(0);
    }
    BARX();
    RD(1, 0, buf);
    if (pre) STG(nx * 4 + 2, gB, ko + 32);  // B_h1(t+1)
    MFMA8();
    // ---- P3: k-step 3 ----
    BARX();
    RD(1, 1, buf);
    if (pre) STG(nx * 4 + 3, gA, ko + 32);  // A_h1(t+1)
    MFMA8();
  }
  // ---- epilogue: gout[m][col] = u * elu(g); ni 0 = up block, ni 1 = gate ----
  const int colb = ((n0 + wn) >> 1) + l31;
#pragma unroll
  for (int mi = 0; mi < 4; ++mi)
#pragma unroll
    for (int reg = 0; reg < 16; ++reg) {
      const int m = m0 + wm + mi * 32 + (reg & 3) + 8 * (reg >> 2) + 4 * half;
      const float uu = acc[mi][0][reg], gg = acc[mi][1][reg];
      const float e = gg > 0.f ? gg : (__expf(gg) - 1.f);
      gout[(size_t)m * F_DIM + colb] = f2bf(uu * e);
    }
#undef STG
#undef RD
#undef MFMA8
}

// ---------------- 256x128 triple-buffered pipelined down GEMM ----------------
// out = aux + A(8192x4096,bf16) x Bt(1024x4096,bf16)^T.  BM=256, BN=128, BK=64.
// 256 thr = 4 waves (2M x 2N), per-wave 128x64 = 4x2 of 32x32 mfma32.
// Grid 32x8 = 256 blocks = exactly 1/CU (zero tail); XCD remap: each XCD owns an
// M-strip (A-panels L2-resident, B re-reads L3-served).
// LDS: 3 buffers x 48KB = 144KB. Buffer: [B_h0 8K][A_h0 16K][B_h1 8K][A_h1 16K].
// Region rows are 32 shorts; swizzle s(r) = (r^(r>>2))&3 as elsewhere.
// 2 phases per K-tile (half hh = 32 k each). Phase: vmcnt(18) [3 halves = 18 loads
// stay in flight]; barrier; 6 ds_read_b128 (k-step 0); issue half hh of tile t+2
// (6 x gl_lds16); 8 mfma32; 6 ds_read (k-step 1); 8 mfma32.
// Tail peels vmcnt 18 -> 12 -> 6 -> 0.
__global__ __launch_bounds__(256, 1) void gemm_down(
    const unsigned short* __restrict__ A, const unsigned short* __restrict__ Bt,
    const float* __restrict__ aux, float* __restrict__ fout) {
  constexpr int KD = 4096;
  constexpr int NT = KD / 64;  // 64 K-tiles
  __shared__ unsigned short L[3 * 24576];  // 144 KiB
  const int tid = threadIdx.x;
  const int lane = tid & 63, w = tid >> 6;
  const int l31 = lane & 31, half = lane >> 5;
  const int wm = (w >> 1) * 128, wn = (w & 1) * 64;
  // XCD-aware remap (bijective, 256 blocks): xcd = f&7 owns m-strip xcd*4..xcd*4+3
  const int f = blockIdx.y * 8 + blockIdx.x;
  const int xcd = f & 7, loc = f >> 3;
  const int m0 = (xcd * 4 + (loc >> 3)) * 256;
  const int n0 = (loc & 7) * 128;
  const int r = tid >> 2;
  const int csrc = ((tid & 3) ^ ((r ^ (r >> 2)) & 3)) * 8;  // shorts
  const unsigned short* gA = A + (size_t)(m0 + r) * KD + csrc;
  const unsigned short* gB = Bt + (size_t)(n0 + r) * KD + csrc;
  const int ldst = tid * 8;
  const int sA = (l31 ^ (l31 >> 2)) & 3;

  f32x16 acc[4][2] = {};
  bf16x8 a[4], b[2];

  // stage half hh of K-tile tt into buffer bufw: B 2 rounds, A 4 rounds (64 rows ea)
#define STG_HALF(hh, tt, bufw)                                                 \
  do {                                                                         \
    const size_t ko = (size_t)(tt) * 64 + (hh) * 32;                           \
    unsigned short* Lb = &L[(bufw) * 24576 + (hh) * 12288];                    \
    gl_lds16(gB + ko, Lb + ldst);                                              \
    gl_lds16(gB + ko + (size_t)64 * KD, Lb + 2048 + ldst);                     \
    gl_lds16(gA + ko, Lb + 4096 + ldst);                                       \
    gl_lds16(gA + ko + (size_t)64 * KD, Lb + 6144 + ldst);                     \
    gl_lds16(gA + ko + (size_t)128 * KD, Lb + 8192 + ldst);                    \
    gl_lds16(gA + ko + (size_t)192 * KD, Lb + 10240 + ldst);                   \
    FENCE();                                                                   \
  } while (0)

#define RDF(kl, hh, base_)                                                     \
  do {                                                                         \
    const int xo = (((kl) * 2 + half) ^ sA) * 8;                               \
    const unsigned short* Lr = &L[(base_) + (hh) * 12288];                     \
    _Pragma("unroll") for (int ni = 0; ni < 2; ++ni)                           \
        b[ni] = *reinterpret_cast<const bf16x8*>(                              \
            &Lr[(wn + ni * 32 + l31) * 32 + xo]);                              \
    _Pragma("unroll") for (int mi = 0; mi < 4; ++mi)                           \
        a[mi] = *reinterpret_cast<const bf16x8*>(                              \
            &Lr[4096 + (wm + mi * 32 + l31) * 32 + xo]);                       \
  } while (0)

#define MFMA8D()                                                               \
  do {                                                                         \
    __builtin_amdgcn_s_setprio(1);                                             \
    _Pragma("unroll") for (int mi = 0; mi < 4; ++mi)                           \
        _Pragma("unroll") for (int ni = 0; ni < 2; ++ni)                       \
            acc[mi][ni] = mfma32(a[mi], b[ni], acc[mi][ni]);                   \
    __builtin_amdgcn_s_setprio(0);                                             \
  } while (0)

#define PHASED(hh, bufr, VM, tt_issue, bufw, DO_ISSUE)                         \
  do {                                                                         \
    VMW(VM);                                                                   \
    BARX();                                                                    \
    const int base_ = (bufr) * 24576;                                          \
    RDF(0, hh, base_);                                                         \
    if (DO_ISSUE) STG_HALF(hh, tt_issue, bufw);                                \
    MFMA8D();                                                                  \
    RDF(1, hh, base_);                                                         \
    MFMA8D();                                                                  \
  } while (0)

  // prologue: stage tiles 0 and 1 (order pinned: h0(0), h1(0), h0(1), h1(1))
  STG_HALF(0, 0, 0);
  STG_HALF(1, 0, 0);
  STG_HALF(0, 1, 1);
  STG_HALF(1, 1, 1);

  int br = 0;
  for (int t = 0; t < NT - 2; ++t) {
    const int bw = (br >= 1) ? br - 1 : br + 2;  // (br+2)%3
    PHASED(0, br, 18, t + 2, bw, true);
    PHASED(1, br, 18, t + 2, bw, true);
    br = (br == 2) ? 0 : br + 1;
  }
  // t = NT-2: nothing left to issue; drain counts drop
  PHASED(0, br, 18, 0, 0, false);
  PHASED(1, br, 12, 0, 0, false);
  br = (br == 2) ? 0 : br + 1;
  // t = NT-1
  PHASED(0, br, 6, 0, 0, false);
  PHASED(1, br, 0, 0, 0, false);

  // epilogue: fout = aux + acc
#pragma unroll
  for (int mi = 0; mi < 4; ++mi)
#pragma unroll
    for (int ni = 0; ni < 2; ++ni) {
      const int n = n0 + wn + ni * 32 + l31;
#pragma unroll
      for (int reg = 0; reg < 16; ++reg) {
        const int m = m0 + wm + mi * 32 + (reg & 3) + 8 * (reg >> 2) + 4 * half;
        const size_t idx = (size_t)m * 1024 + n;
        fout[idx] = aux[idx] + acc[mi][ni][reg];
      }
    }
#undef STG_HALF
#undef RDF
#undef MFMA8D
#undef PHASED
}

// ---------------- flash attention (causal), BQ=128, BKV=64 ----------------
// q pre-scaled by 1/8; fixed-shift softmax: p = exp(s - 8) (exact, scores bounded).
// K/V tiles XOR-swizzled (conflict-free frag reads). LPT: qt descending.
#define PS_STRIDE 68  // 136B rows: 8B-aligned, quad bank offset 8 -> conflict-free writes
__global__ __launch_bounds__(256) void flash_attn(
    const unsigned short* __restrict__ qb, const unsigned short* __restrict__ kb,
    const unsigned short* __restrict__ vtb, unsigned short* __restrict__ attn) {
  __shared__ unsigned short Ks[64 * 64];
  __shared__ unsigned short Vts[64 * 64];  // [d][t_local]
  __shared__ unsigned short Ps[128 * PS_STRIDE];
  const int t = threadIdx.x, lane = t & 63, w = t >> 6;
  const int quad = lane >> 4, l15 = lane & 15;
  const int qt = 15 - blockIdx.y;  // LPT: longest blocks dispatch first
  const int bh = blockIdx.x;
  const int b = bh >> 4, hh = bh & 15;
  const unsigned short* qg = qb + (size_t)bh * S_LEN * 64;
  const unsigned short* kg = kb + (size_t)bh * S_LEN * 64;
  const unsigned short* vg = vtb + (size_t)bh * 64 * S_LEN;
  // Q fragments: iteration-invariant, load straight to registers (A-layout)
  bf16x8 aq[2][2];
#pragma unroll
  for (int mi = 0; mi < 2; ++mi)
#pragma unroll
    for (int ks = 0; ks < 2; ++ks)
      aq[mi][ks] = *reinterpret_cast<const bf16x8*>(
          qg + (size_t)(qt * 128 + w * 32 + mi * 16 + l15) * 64 + ks * 32 + quad * 8);
  f32x4 o[2][4] = {};
  float lpart[2][4] = {};  // per-lane partial softmax denominators
  const int srk = t >> 3, sck = t & 7;
  const int gck = ((sck ^ (srk & 7)) * 8);  // swizzled global chunk (shorts)
  const int xh = l15 & 7;
  const int ktmax = 2 * qt + 1;
  for (int kt = 0; kt <= ktmax; ++kt) {
    __syncthreads();
#pragma unroll
    for (int i = 0; i < 2; ++i) {
      gl_lds16(kg + (size_t)(kt * 64 + srk + i * 32) * 64 + gck,
               &Ks[(srk + i * 32) * 64 + sck * 8]);
      gl_lds16(vg + (size_t)(srk + i * 32) * S_LEN + kt * 64 + gck,
               &Vts[(srk + i * 32) * 64 + sck * 8]);
    }
    __syncthreads();
    // S = q.k/8 - 8 (shift folded into accumulator init)
    f32x4 sacc[2][4];
#pragma unroll
    for (int mi = 0; mi < 2; ++mi)
#pragma unroll
      for (int nt = 0; nt < 4; ++nt) sacc[mi][nt] = (f32x4){-8.f, -8.f, -8.f, -8.f};
#pragma unroll
    for (int nt = 0; nt < 4; ++nt) {
      bf16x8 b0 = *reinterpret_cast<const bf16x8*>(
          &Ks[(nt * 16 + l15) * 64 + ((quad ^ xh) * 8)]);
      bf16x8 b1 = *reinterpret_cast<const bf16x8*>(
          &Ks[(nt * 16 + l15) * 64 + (((4 + quad) ^ xh) * 8)]);
#pragma unroll
      for (int mi = 0; mi < 2; ++mi) {
        sacc[mi][nt] = mfma16(aq[mi][0], b0, sacc[mi][nt]);
        sacc[mi][nt] = mfma16(aq[mi][1], b1, sacc[mi][nt]);
      }
    }
    if (kt >= 2 * qt) {  // diagonal tiles: causal mask
#pragma unroll
      for (int mi = 0; mi < 2; ++mi)
#pragma unroll
        for (int nt = 0; nt < 4; ++nt)
#pragma unroll
          for (int rg = 0; rg < 4; ++rg) {
            const int row = qt * 128 + w * 32 + mi * 16 + quad * 4 + rg;
            const int col = kt * 64 + nt * 16 + l15;
            if (col > row) sacc[mi][nt][rg] = -1e9f;
          }
    }
    // p = exp(s-8); accumulate per-lane l; write P to LDS (bf16, padded rows)
#pragma unroll
    for (int mi = 0; mi < 2; ++mi)
#pragma unroll
      for (int nt = 0; nt < 4; ++nt)
#pragma unroll
        for (int rg = 0; rg < 4; ++rg) {
          const float p = __expf(sacc[mi][nt][rg]);
          lpart[mi][rg] += p;
          Ps[(w * 32 + mi * 16 + quad * 4 + rg) * PS_STRIDE + nt * 16 + l15] = f2bf(p);
        }
    // PV: same-wave LDS round-trip (rows w*32..w*32+31 only, no barrier needed)
#pragma unroll
    for (int ks = 0; ks < 2; ++ks) {
      bf16x8 ap[2];
#pragma unroll
      for (int mi = 0; mi < 2; ++mi) {
        const unsigned short* pp =
            &Ps[(w * 32 + mi * 16 + l15) * PS_STRIDE + ks * 32 + quad * 8];
        bf16x4 lo = *reinterpret_cast<const bf16x4*>(pp);
        bf16x4 hi = *reinterpret_cast<const bf16x4*>(pp + 4);
        ap[mi] = __builtin_shufflevector(lo, hi, 0, 1, 2, 3, 4, 5, 6, 7);
      }
#pragma unroll
      for (int vt = 0; vt < 4; ++vt) {
        bf16x8 bv = *reinterpret_cast<const bf16x8*>(
            &Vts[(vt * 16 + l15) * 64 + (((ks * 4 + quad) ^ xh) * 8)]);
#pragma unroll
        for (int mi = 0; mi < 2; ++mi) o[mi][vt] = mfma16(ap[mi], bv, o[mi][vt]);
      }
    }
  }
  // final denominator reduce across the 16 col-lanes of each row
  float linv[2][4];
#pragma unroll
  for (int mi = 0; mi < 2; ++mi)
#pragma unroll
    for (int rg = 0; rg < 4; ++rg) {
      float rs = lpart[mi][rg];
#pragma unroll
      for (int d = 1; d < 16; d <<= 1) rs += __shfl_xor(rs, d);
      linv[mi][rg] = 1.0f / rs;
    }
#pragma unroll
  for (int mi = 0; mi < 2; ++mi)
#pragma unroll
    for (int vt = 0; vt < 4; ++vt)
#pragma unroll
      for (int rg = 0; rg < 4; ++rg) {
        const int row = w * 32 + mi * 16 + quad * 4 + rg;
        const int s = qt * 128 + row;
        const float ov = o[mi][vt][rg] * linv[mi][rg];
        attn[((size_t)(b * S_LEN + s)) * E_DIM + hh * 64 + vt * 16 + l15] = f2bf(ov);
      }
}

// ---------------- rmsnorm: h = x * rsqrt(mean(x^2)+eps) * w  (bf16 out) ----------------
__global__ __launch_bounds__(256) void rmsnorm_kernel(
    const float* __restrict__ x, const float* __restrict__ wgt,
    unsigned short* __restrict__ hout) {
  const int row = blockIdx.x;
  const int t = threadIdx.x;
  const float4 v = reinterpret_cast<const float4*>(x + (size_t)row * E_DIM)[t];
  float ss = v.x * v.x + v.y * v.y + v.z * v.z + v.w * v.w;
#pragma unroll
  for (int d = 1; d < 64; d <<= 1) ss += __shfl_xor(ss, d);
  __shared__ float red[4];
  if ((t & 63) == 0) red[t >> 6] = ss;
  __syncthreads();
  const float tot = red[0] + red[1] + red[2] + red[3];
  const float sc = rsqrtf(tot * (1.f / 1024.f) + 1.1920929e-07f);
  const float4 g = reinterpret_cast<const float4*>(wgt)[t];
  ushort4 ov;
  ov.x = f2bf(v.x * sc * g.x);
  ov.y = f2bf(v.y * sc * g.y);
  ov.z = f2bf(v.z * sc * g.z);
  ov.w = f2bf(v.w * sc * g.w);
  reinterpret_cast<ushort4*>(hout + (size_t)row * E_DIM)[t] = ov;
}

// ---------------- host ----------------
extern "C" void kernel_launch(void* const* d_in, const int* in_sizes, int n_in,
                              void* d_out, int out_size, void* d_ws, size_t ws_size,
                              hipStream_t stream) {
  (void)in_sizes; (void)n_in; (void)out_size; (void)ws_size;
  const float* emb = (const float*)d_in[0];
  const float* cosb = (const float*)d_in[2];
  const float* sinb = (const float*)d_in[3];
  const float* wq = (const float*)d_in[4];
  const float* wk = (const float*)d_in[5];
  const float* wv = (const float*)d_in[6];
  const float* wproj = (const float*)d_in[7];
  const float* mlpw = (const float*)d_in[9];
  const float* wup = (const float*)d_in[10];
  const float* wgate = (const float*)d_in[11];
  const float* wdown = (const float*)d_in[12];
  float* out = (float*)d_out;
  char* ws = (char*)d_ws;
  // layout (bytes): weights 32MiB | shared67 (emb_bf16,q,k,vt | aliased later by g) | attn | x | h
  unsigned short* wqkv_t = (unsigned short*)(ws + 0);
  unsigned short* wproj_t = (unsigned short*)(ws + 6291456);
  unsigned short* wupgate_t = (unsigned short*)(ws + 8388608);  // interleave-32 U/G, 8192x1024
  unsigned short* wdown_t = (unsigned short*)(ws + 25165824);
  unsigned short* embb = (unsigned short*)(ws + 33554432);
  unsigned short* qbuf = (unsigned short*)(ws + 50331648);
  unsigned short* kbuf = (unsigned short*)(ws + 67108864);
  unsigned short* vtbuf = (unsigned short*)(ws + 83886080);
  unsigned short* gbuf = (unsigned short*)(ws + 33554432);  // aliases embb..vtbuf (dead by then)
  unsigned short* attnb = (unsigned short*)(ws + 100663296);
  float* xbuf = (float*)(ws + 117440512);
  unsigned short* hbuf = (unsigned short*)(ws + 150994944);

  dim3 blk(256);
  // prep: casts + transposes to B^T layouts
  cast_emb_kernel<<<8192, blk, 0, stream>>>((const float4*)emb, (ushort4*)embb);
  transpose_cast_qkv<<<dim3(2, 32, 48), blk, 0, stream>>>(wq, wk, wv, wqkv_t);
  transpose_cast_kernel<<<dim3(32, 32, 1), blk, 0, stream>>>(wproj, wproj_t, 1024, 1024);
  transpose_cast_upgate<<<dim3(128, 32, 2), blk, 0, stream>>>(wup, wgate, wupgate_t);
  transpose_cast_kernel<<<dim3(32, 128, 1), blk, 0, stream>>>(wdown, wdown_t, 4096, 1024);
  // QKV + RoPE (q pre-scaled by 1/8)
  gemm_bt<0, 1024><<<dim3(24, 64), blk, 0, stream>>>(
      embb, wqkv_t, nullptr, cosb, sinb, qbuf, kbuf, vtbuf, nullptr, nullptr);
  // causal flash attention (LPT order)
  flash_attn<<<dim3(64, 16), blk, 0, stream>>>(qbuf, kbuf, vtbuf, attnb);
  // proj + residual -> x (fp32)
  gemm_bt<1, 1024><<<dim3(8, 64), blk, 0, stream>>>(
      attnb, wproj_t, emb, nullptr, nullptr, nullptr, nullptr, nullptr, xbuf, nullptr);
  // rmsnorm -> h (bf16)
  rmsnorm_kernel<<<8192, blk, 0, stream>>>(xbuf, mlpw, hbuf);
  // fused up/gate (interleave-32 B, 256^2 4-phase pipelined, mfma32) -> g (bf16)
  gemm256_upgate<<<dim3(32, 32), dim3(512), 0, stream>>>(hbuf, wupgate_t, gbuf);
  // down + residual -> out (fp32): 256x128 triple-buffered pipeline, 1 block/CU
  gemm_down<<<dim3(8, 32), blk, 0, stream>>>(gbuf, wdown_t, xbuf, out);
}

// Round 4
// 555.721 us; speedup vs baseline: 1.1418x; 1.0704x over previous
//
#include <hip/hip_runtime.h>
#include <cstdint>
#include <cstddef>

#define E_DIM 1024
#define S_LEN 2048
#define NB 4
#define NH 16
#define F_DIM 4096

typedef __attribute__((ext_vector_type(8))) __bf16 bf16x8;
typedef __attribute__((ext_vector_type(4))) __bf16 bf16x4;
typedef __attribute__((ext_vector_type(4))) float f32x4;
typedef __attribute__((ext_vector_type(16))) float f32x16;

__device__ __forceinline__ f32x4 mfma16(bf16x8 a, bf16x8 b, f32x4 c) {
  return __builtin_amdgcn_mfma_f32_16x16x32_bf16(a, b, c, 0, 0, 0);
}
__device__ __forceinline__ f32x16 mfma32(bf16x8 a, bf16x8 b, f32x16 c) {
  return __builtin_amdgcn_mfma_f32_32x32x16_bf16(a, b, c, 0, 0, 0);
}

// fp32 -> bf16 bits via HW convert (RNE)
__device__ __forceinline__ unsigned short f2bf(float f) {
  __bf16 h = (__bf16)f;
  return __builtin_bit_cast(unsigned short, h);
}

// async global->LDS, 16B per lane. LDS dest must be wave-uniform base + lane*16.
__device__ __forceinline__ void gl_lds16(const void* gptr, void* lptr) {
  __builtin_amdgcn_global_load_lds(
      (const __attribute__((address_space(1))) void*)gptr,
      (__attribute__((address_space(3))) void*)lptr, 16, 0, 0);
}

// ---------------- prep kernels ----------------

__global__ __launch_bounds__(256) void cast_emb_kernel(
    const float4* __restrict__ in, ushort4* __restrict__ out) {
  int i = blockIdx.x * 256 + threadIdx.x;
  float4 v = in[i];
  ushort4 o;
  o.x = f2bf(v.x); o.y = f2bf(v.y); o.z = f2bf(v.z); o.w = f2bf(v.w);
  out[i] = o;
}

// generic: in [batch][R][C] fp32 -> out[(bz*C+c)*R + r] bf16
__global__ __launch_bounds__(256) void transpose_cast_kernel(
    const float* __restrict__ in, unsigned short* __restrict__ out, int R, int C) {
  __shared__ float tile[32][33];
  const int bz = blockIdx.z;
  const float* ip = in + (size_t)bz * R * C;
  const int r0 = blockIdx.y * 32, c0 = blockIdx.x * 32;
  const int tc = threadIdx.x & 31, tr = threadIdx.x >> 5;  // tr 0..7
#pragma unroll
  for (int i = 0; i < 4; ++i)
    tile[tr + i * 8][tc] = ip[(size_t)(r0 + tr + i * 8) * C + (c0 + tc)];
  __syncthreads();
#pragma unroll
  for (int i = 0; i < 4; ++i)
    out[(size_t)(bz * C + c0 + tr + i * 8) * R + (r0 + tc)] = f2bf(tile[tc][tr + i * 8]);
}

// QKV weights: 3 x [16][1024][64] -> one B^T buffer [3072][1024]
__global__ __launch_bounds__(256) void transpose_cast_qkv(
    const float* __restrict__ wq, const float* __restrict__ wk,
    const float* __restrict__ wv, unsigned short* __restrict__ out) {
  __shared__ float tile[32][33];
  const int bz = blockIdx.z;  // 0..47
  const int which = bz >> 4, hz = bz & 15;
  const float* ip =
      (which == 0 ? wq : which == 1 ? wk : wv) + (size_t)hz * 1024 * 64;
  unsigned short* op = out + (size_t)which * 1024 * 1024;
  const int r0 = blockIdx.y * 32, c0 = blockIdx.x * 32;
  const int tc = threadIdx.x & 31, tr = threadIdx.x >> 5;
#pragma unroll
  for (int i = 0; i < 4; ++i)
    tile[tr + i * 8][tc] = ip[(size_t)(r0 + tr + i * 8) * 64 + (c0 + tc)];
  __syncthreads();
#pragma unroll
  for (int i = 0; i < 4; ++i)
    op[(size_t)(hz * 64 + c0 + tr + i * 8) * 1024 + (r0 + tc)] =
        f2bf(tile[tc][tr + i * 8]);
}

// up/gate -> interleave-32 B^T: row = 64*(c>>5) + (c&31) + z*32  (z: 0=up,1=gate)
__global__ __launch_bounds__(256) void transpose_cast_upgate(
    const float* __restrict__ wup, const float* __restrict__ wgate,
    unsigned short* __restrict__ out) {
  __shared__ float tile[32][33];
  const int z = blockIdx.z & 1;
  const float* ip = z ? wgate : wup;
  const int r0 = blockIdx.y * 32, c0 = blockIdx.x * 32;
  const int tc = threadIdx.x & 31, tr = threadIdx.x >> 5;
#pragma unroll
  for (int i = 0; i < 4; ++i)
    tile[tr + i * 8][tc] = ip[(size_t)(r0 + tr + i * 8) * F_DIM + (c0 + tc)];
  __syncthreads();
#pragma unroll
  for (int i = 0; i < 4; ++i) {
    const int c = c0 + tr + i * 8;
    const int row = 64 * (c >> 5) + (c & 31) + z * 32;
    out[(size_t)row * E_DIM + (r0 + tc)] = f2bf(tile[tc][tr + i * 8]);
  }
}

// ------- 128x128 bf16 GEMM, B^T input, BK=64, XOR-swizzled LDS, 32x32x16 MFMA ---
// Wave computes 64x64 as 2x2 of 32x32 tiles. A/B frag: [m=lane&31][k=(lane>>5)*8+j].
// C/D: col = lane&31, row = (reg&3) + 8*(reg>>2) + 4*(lane>>5).
// EPI 1: fout[idx] = aux[idx] + acc (proj->x), N must be 1024.
template <int EPI, int KD>
__global__ __launch_bounds__(256) void gemm_bt(
    const unsigned short* __restrict__ A, const unsigned short* __restrict__ Bt,
    const float* __restrict__ aux, float* __restrict__ fout) {
  __shared__ unsigned short As[128 * 64];
  __shared__ unsigned short Bs[128 * 64];
  const int t = threadIdx.x;
  const int lane = t & 63, w = t >> 6;
  const int l31 = lane & 31, half = lane >> 5;
  const int wm = (w >> 1) * 64, wn = (w & 1) * 64;
  const int m0 = blockIdx.y * 128, n0 = blockIdx.x * 128;
  // staging: thread t -> LDS row sr, phys chunk (t&7); global chunk = (t&7)^(sr&7)
  const int sr = t >> 3, sc = t & 7;
  const int gcoff = (sc ^ (sr & 7)) * 8;  // shorts
  const unsigned short* ga = A + (size_t)(m0 + sr) * KD + gcoff;
  const unsigned short* gb = Bt + (size_t)(n0 + sr) * KD + gcoff;
  unsigned short* lA = &As[sr * 64 + sc * 8];
  unsigned short* lB = &Bs[sr * 64 + sc * 8];
  const int xh = lane & 7;  // fragment-read swizzle key (= row&7 for frag rows)
  f32x16 acc[2][2] = {};
  for (int k0 = 0; k0 < KD; k0 += 64) {
    __syncthreads();
#pragma unroll
    for (int i = 0; i < 4; ++i) {
      gl_lds16(ga + (size_t)(i * 32) * KD + k0, lA + i * 32 * 64);
      gl_lds16(gb + (size_t)(i * 32) * KD + k0, lB + i * 32 * 64);
    }
    __syncthreads();
#pragma unroll
    for (int ksl = 0; ksl < 4; ++ksl) {
      const int cp = ((ksl * 2 + half) ^ xh) * 8;
      bf16x8 af[2], bfr[2];
#pragma unroll
      for (int mi = 0; mi < 2; ++mi)
        af[mi] = *reinterpret_cast<const bf16x8*>(&As[(wm + mi * 32 + l31) * 64 + cp]);
#pragma unroll
      for (int ni = 0; ni < 2; ++ni)
        bfr[ni] = *reinterpret_cast<const bf16x8*>(&Bs[(wn + ni * 32 + l31) * 64 + cp]);
#pragma unroll
      for (int mi = 0; mi < 2; ++mi)
#pragma unroll
        for (int ni = 0; ni < 2; ++ni)
          acc[mi][ni] = mfma32(af[mi], bfr[ni], acc[mi][ni]);
    }
  }
#pragma unroll
  for (int mi = 0; mi < 2; ++mi)
#pragma unroll
    for (int ni = 0; ni < 2; ++ni) {
      const int n = n0 + wn + ni * 32 + l31;
#pragma unroll
      for (int reg = 0; reg < 16; ++reg) {
        const int m = m0 + wm + mi * 32 + (reg & 3) + 8 * (reg >> 2) + 4 * half;
        const size_t idx = (size_t)m * 1024 + n;
        fout[idx] = aux[idx] + acc[mi][ni][reg];
      }
    }
}

// ---------------- 256x256 4-phase pipelined GEMM (templated epilogue) ----------------
// BM=BN=256, BK=64, 512 thr = 8 waves (2M x 4N), per-wave 128x64 = 4x2 of 32x32,
// 32x32x16 MFMA. LDS: 8 regions x 16KB (2 buffers x {B_h0, A_h0, B_h1, A_h1});
// region = 256 rows x 32 shorts. Swizzle: phys chunk = logical ^ s(row),
// s(r) = (r ^ (r>>2)) & 3 (2-way floor on b128 reads).
// Counted vmcnt(4) at P0/P2 only; 4 pairs (8 loads) in flight across barriers.
// EPI 0: QKV+RoPE. N=3072, grid 12x32 XCD-chunked. Whole block is one seg
//   (q/k/v). q/k: RoPE pair = (ni0, ni1) cols kk / kk^32; q scaled 1/8.
//   v: vT scatter with ushort4-packed stores (4 s-contiguous regs per store).
// EPI 3: up/gate interleave-32: ni0 = up, ni1 = gate; gout = u*elu(g).
#define FENCE() asm volatile("" ::: "memory")
#define BARX()                        \
  do {                                \
    FENCE();                          \
    __builtin_amdgcn_s_barrier();     \
    FENCE();                          \
  } while (0)
#define VMW_(n) asm volatile("s_waitcnt vmcnt(" #n ")" ::: "memory")
#define VMW(n) VMW_(n)

template <int EPI>
__global__ __launch_bounds__(512, 2) void gemm256(
    const unsigned short* __restrict__ A, const unsigned short* __restrict__ Bt,
    const float* __restrict__ cosb, const float* __restrict__ sinb,
    unsigned short* __restrict__ qout, unsigned short* __restrict__ kout,
    unsigned short* __restrict__ vtout, unsigned short* __restrict__ gout) {
  constexpr int KD = 1024;
  constexpr int NT = KD / 64;  // 16 K-tiles
  __shared__ unsigned short L[8 * 8192];  // 128 KiB
  const int tid = threadIdx.x;
  const int lane = tid & 63, w = tid >> 6;
  const int l31 = lane & 31, half = lane >> 5;
  const int wm = (w >> 2) * 128, wn = (w & 3) * 64;
  int m0, n0;
  if (EPI == 0) {
    // 384 blocks; bijective XCD chunking: each XCD owns 48 contiguous blocks
    // (4 m-rows x 12 n) -> per-XCD A working set 2MB (L2-resident).
    const int f = blockIdx.y * 12 + blockIdx.x;
    const int fl = (f & 7) * 48 + (f >> 3);
    m0 = (fl / 12) * 256;
    n0 = (fl % 12) * 256;
  } else {
    m0 = blockIdx.y * 256;
    n0 = blockIdx.x * 256;
  }
  const int r = tid >> 2;
  const int csrc = ((tid & 3) ^ ((r ^ (r >> 2)) & 3)) * 8;  // shorts
  const unsigned short* gA = A + (size_t)(m0 + r) * KD + csrc;
  const unsigned short* gB = Bt + (size_t)(n0 + r) * KD + csrc;
  const int ldst = tid * 8;  // shorts: linear 16B/lane dest within region
  const int sA = (l31 ^ (l31 >> 2)) & 3;  // read swizzle key (= s(row) for frag rows)

  f32x16 acc[4][2] = {};
  bf16x8 a[4], b[2];

#define STG(ridx, gp, koff)                                                    \
  do {                                                                         \
    gl_lds16((gp) + (koff), &L[(ridx) * 8192 + ldst]);                         \
    gl_lds16((gp) + (koff) + (size_t)128 * KD,                                 \
             &L[(ridx) * 8192 + 4096 + ldst]);                                 \
  } while (0)

#define RD(hh, kl, bufi)                                                       \
  do {                                                                         \
    const int xo = ((((kl) * 2 + half) ^ sA)) * 8;                             \
    const int ra = ((bufi) * 4 + 1 + 2 * (hh)) * 8192;                         \
    const int rb = ((bufi) * 4 + 2 * (hh)) * 8192;                             \
    _Pragma("unroll") for (int mi = 0; mi < 4; ++mi)                           \
        a[mi] = *reinterpret_cast<const bf16x8*>(                              \
            &L[ra + (wm + mi * 32 + l31) * 32 + xo]);                          \
    _Pragma("unroll") for (int ni = 0; ni < 2; ++ni)                           \
        b[ni] = *reinterpret_cast<const bf16x8*>(                              \
            &L[rb + (wn + ni * 32 + l31) * 32 + xo]);                          \
  } while (0)

#define MFMA8()                                                                \
  do {                                                                         \
    __builtin_amdgcn_s_setprio(1);                                             \
    _Pragma("unroll") for (int mi = 0; mi < 4; ++mi)                           \
        _Pragma("unroll") for (int ni = 0; ni < 2; ++ni)                       \
            acc[mi][ni] = mfma32(a[mi], b[ni], acc[mi][ni]);                   \
    __builtin_amdgcn_s_setprio(0);                                             \
  } while (0)

  // prologue: tile 0's 4 pairs into buffer 0 (issue order pinned for vmcnt math)
  STG(0, gB, 0); FENCE();
  STG(1, gA, 0); FENCE();
  STG(2, gB, 32); FENCE();
  STG(3, gA, 32); FENCE();

  int buf = 0;
  for (int t = 0; t < NT; ++t, buf ^= 1) {
    const int nx = buf ^ 1;
    const bool pre = (t + 1 < NT);
    const int ko = (t + 1) * 64;
    // ---- P0: k-step 0 (pairs B_h0, A_h0 of tile t) ----
    VMW(4);
    BARX();
    RD(0, 0, buf);
    if (pre) STG(nx * 4 + 0, gB, ko);  // B_h0(t+1)
    MFMA8();
    // ---- P1: k-step 1 ----
    BARX();
    RD(0, 1, buf);
    if (pre) STG(nx * 4 + 1, gA, ko);  // A_h0(t+1)
    MFMA8();
    // ---- P2: k-step 2 (pairs B_h1, A_h1) ----
    if (pre) {
      VMW(4);
    } else {
      VMW(0);
    }
    BARX();
    RD(1, 0, buf);
    if (pre) STG(nx * 4 + 2, gB, ko + 32);  // B_h1(t+1)
    MFMA8();
    // ---- P3: k-step 3 ----
    BARX();
    RD(1, 1, buf);
    if (pre) STG(nx * 4 + 3, gA, ko + 32);  // A_h1(t+1)
    MFMA8();
  }

  if (EPI == 3) {
    // gout[m][col] = u * elu(g); ni 0 = up block, ni 1 = gate
    const int colb = ((n0 + wn) >> 1) + l31;
#pragma unroll
    for (int mi = 0; mi < 4; ++mi)
#pragma unroll
      for (int reg = 0; reg < 16; ++reg) {
        const int m = m0 + wm + mi * 32 + (reg & 3) + 8 * (reg >> 2) + 4 * half;
        const float uu = acc[mi][0][reg], gg = acc[mi][1][reg];
        const float e = gg > 0.f ? gg : (__expf(gg) - 1.f);
        gout[(size_t)m * F_DIM + colb] = f2bf(uu * e);
      }
  } else {
    const int seg = n0 >> 10;         // whole block in one seg (q=0,k=1,v=2)
    const int nl = (n0 & 1023) + wn;  // multiple of 64
    if (seg == 2) {
      // vT: packed stores, 4 s-contiguous regs -> one ushort4 (8B)
#pragma unroll
      for (int mi = 0; mi < 4; ++mi)
#pragma unroll
        for (int ni = 0; ni < 2; ++ni) {
          const int rest = nl + ni * 32 + l31;
          const int hh = rest >> 6, kk = rest & 63;
#pragma unroll
          for (int g = 0; g < 4; ++g) {
            const int m = m0 + wm + mi * 32 + 8 * g + 4 * half;  // s run base
            const int bb = m >> 11, s = m & 2047;
            ushort4 pk;
            pk.x = f2bf(acc[mi][ni][g * 4 + 0]);
            pk.y = f2bf(acc[mi][ni][g * 4 + 1]);
            pk.z = f2bf(acc[mi][ni][g * 4 + 2]);
            pk.w = f2bf(acc[mi][ni][g * 4 + 3]);
            *reinterpret_cast<ushort4*>(
                &vtout[(((size_t)(bb * NH + hh)) * 64 + kk) * S_LEN + s]) = pk;
          }
        }
    } else {
      unsigned short* dst = (seg == 0) ? qout : kout;
      const float scl = (seg == 0) ? 0.125f : 1.0f;  // fold 1/sqrt(K) into q
#pragma unroll
      for (int mi = 0; mi < 4; ++mi)
#pragma unroll
        for (int ni = 0; ni < 2; ++ni) {
          const int rest = nl + ni * 32 + l31;
          const int hh = rest >> 6, kk = rest & 63;
#pragma unroll
          for (int reg = 0; reg < 16; ++reg) {
            const int m =
                m0 + wm + mi * 32 + (reg & 3) + 8 * (reg >> 2) + 4 * half;
            const int bb = m >> 11, s = m & 2047;
            const float v = acc[mi][ni][reg];
            const float sw = acc[mi][ni ^ 1][reg];  // col kk^32
            const float cv = cosb[s * 64 + kk], sv = sinb[s * 64 + kk];
            dst[(((size_t)(bb * NH + hh)) * S_LEN + s) * 64 + kk] =
                f2bf((cv * v + sv * sw) * scl);
          }
        }
    }
  }
#undef STG
#undef RD
#undef MFMA8
}

// ---------------- 256x128 triple-buffered pipelined down GEMM ----------------
// out = aux + A(8192x4096,bf16) x Bt(1024x4096,bf16)^T.  BM=256, BN=128, BK=64.
// 256 thr = 4 waves (2M x 2N), per-wave 128x64 = 4x2 of 32x32 mfma32.
// Grid 32x8 = 256 blocks = exactly 1/CU (zero tail); XCD remap: each XCD owns an
// M-strip. LDS: 3 buffers x 48KB = 144KB. Counted vmcnt(18), tail 18->12->6->0.
__global__ __launch_bounds__(256, 1) void gemm_down(
    const unsigned short* __restrict__ A, const unsigned short* __restrict__ Bt,
    const float* __restrict__ aux, float* __restrict__ fout) {
  constexpr int KD = 4096;
  constexpr int NT = KD / 64;  // 64 K-tiles
  __shared__ unsigned short L[3 * 24576];  // 144 KiB
  const int tid = threadIdx.x;
  const int lane = tid & 63, w = tid >> 6;
  const int l31 = lane & 31, half = lane >> 5;
  const int wm = (w >> 1) * 128, wn = (w & 1) * 64;
  const int f = blockIdx.y * 8 + blockIdx.x;
  const int xcd = f & 7, loc = f >> 3;
  const int m0 = (xcd * 4 + (loc >> 3)) * 256;
  const int n0 = (loc & 7) * 128;
  const int r = tid >> 2;
  const int csrc = ((tid & 3) ^ ((r ^ (r >> 2)) & 3)) * 8;  // shorts
  const unsigned short* gA = A + (size_t)(m0 + r) * KD + csrc;
  const unsigned short* gB = Bt + (size_t)(n0 + r) * KD + csrc;
  const int ldst = tid * 8;
  const int sA = (l31 ^ (l31 >> 2)) & 3;

  f32x16 acc[4][2] = {};
  bf16x8 a[4], b[2];

#define STG_HALF(hh, tt, bufw)                                                 \
  do {                                                                         \
    const size_t ko = (size_t)(tt) * 64 + (hh) * 32;                           \
    unsigned short* Lb = &L[(bufw) * 24576 + (hh) * 12288];                    \
    gl_lds16(gB + ko, Lb + ldst);                                              \
    gl_lds16(gB + ko + (size_t)64 * KD, Lb + 2048 + ldst);                     \
    gl_lds16(gA + ko, Lb + 4096 + ldst);                                       \
    gl_lds16(gA + ko + (size_t)64 * KD, Lb + 6144 + ldst);                     \
    gl_lds16(gA + ko + (size_t)128 * KD, Lb + 8192 + ldst);                    \
    gl_lds16(gA + ko + (size_t)192 * KD, Lb + 10240 + ldst);                   \
    FENCE();                                                                   \
  } while (0)

#define RDF(kl, hh, base_)                                                     \
  do {                                                                         \
    const int xo = (((kl) * 2 + half) ^ sA) * 8;                               \
    const unsigned short* Lr = &L[(base_) + (hh) * 12288];                     \
    _Pragma("unroll") for (int ni = 0; ni < 2; ++ni)                           \
        b[ni] = *reinterpret_cast<const bf16x8*>(                              \
            &Lr[(wn + ni * 32 + l31) * 32 + xo]);                              \
    _Pragma("unroll") for (int mi = 0; mi < 4; ++mi)                           \
        a[mi] = *reinterpret_cast<const bf16x8*>(                              \
            &Lr[4096 + (wm + mi * 32 + l31) * 32 + xo]);                       \
  } while (0)

#define MFMA8D()                                                               \
  do {                                                                         \
    __builtin_amdgcn_s_setprio(1);                                             \
    _Pragma("unroll") for (int mi = 0; mi < 4; ++mi)                           \
        _Pragma("unroll") for (int ni = 0; ni < 2; ++ni)                       \
            acc[mi][ni] = mfma32(a[mi], b[ni], acc[mi][ni]);                   \
    __builtin_amdgcn_s_setprio(0);                                             \
  } while (0)

#define PHASED(hh, bufr, VM, tt_issue, bufw, DO_ISSUE)                         \
  do {                                                                         \
    VMW(VM);                                                                   \
    BARX();                                                                    \
    const int base_ = (bufr) * 24576;                                          \
    RDF(0, hh, base_);                                                         \
    if (DO_ISSUE) STG_HALF(hh, tt_issue, bufw);                                \
    MFMA8D();                                                                  \
    RDF(1, hh, base_);                                                         \
    MFMA8D();                                                                  \
  } while (0)

  STG_HALF(0, 0, 0);
  STG_HALF(1, 0, 0);
  STG_HALF(0, 1, 1);
  STG_HALF(1, 1, 1);

  int br = 0;
  for (int t = 0; t < NT - 2; ++t) {
    const int bw = (br >= 1) ? br - 1 : br + 2;  // (br+2)%3
    PHASED(0, br, 18, t + 2, bw, true);
    PHASED(1, br, 18, t + 2, bw, true);
    br = (br == 2) ? 0 : br + 1;
  }
  PHASED(0, br, 18, 0, 0, false);
  PHASED(1, br, 12, 0, 0, false);
  br = (br == 2) ? 0 : br + 1;
  PHASED(0, br, 6, 0, 0, false);
  PHASED(1, br, 0, 0, 0, false);

#pragma unroll
  for (int mi = 0; mi < 4; ++mi)
#pragma unroll
    for (int ni = 0; ni < 2; ++ni) {
      const int n = n0 + wn + ni * 32 + l31;
#pragma unroll
      for (int reg = 0; reg < 16; ++reg) {
        const int m = m0 + wm + mi * 32 + (reg & 3) + 8 * (reg >> 2) + 4 * half;
        const size_t idx = (size_t)m * 1024 + n;
        fout[idx] = aux[idx] + acc[mi][ni][reg];
      }
    }
#undef STG_HALF
#undef RDF
#undef MFMA8D
#undef PHASED
}

// ---------------- flash attention (causal), BQ=128, BKV=64 ----------------
// q pre-scaled by 1/8; fixed-shift softmax: p = exp(s - 8) (exact, scores bounded).
// K/V tiles XOR-swizzled (conflict-free frag reads). LPT: qt descending.
#define PS_STRIDE 68  // 136B rows: 8B-aligned, quad bank offset 8 -> conflict-free writes
__global__ __launch_bounds__(256) void flash_attn(
    const unsigned short* __restrict__ qb, const unsigned short* __restrict__ kb,
    const unsigned short* __restrict__ vtb, unsigned short* __restrict__ attn) {
  __shared__ unsigned short Ks[64 * 64];
  __shared__ unsigned short Vts[64 * 64];  // [d][t_local]
  __shared__ unsigned short Ps[128 * PS_STRIDE];
  const int t = threadIdx.x, lane = t & 63, w = t >> 6;
  const int quad = lane >> 4, l15 = lane & 15;
  const int qt = 15 - blockIdx.y;  // LPT: longest blocks dispatch first
  const int bh = blockIdx.x;
  const int b = bh >> 4, hh = bh & 15;
  const unsigned short* qg = qb + (size_t)bh * S_LEN * 64;
  const unsigned short* kg = kb + (size_t)bh * S_LEN * 64;
  const unsigned short* vg = vtb + (size_t)bh * 64 * S_LEN;
  // Q fragments: iteration-invariant, load straight to registers (A-layout)
  bf16x8 aq[2][2];
#pragma unroll
  for (int mi = 0; mi < 2; ++mi)
#pragma unroll
    for (int ks = 0; ks < 2; ++ks)
      aq[mi][ks] = *reinterpret_cast<const bf16x8*>(
          qg + (size_t)(qt * 128 + w * 32 + mi * 16 + l15) * 64 + ks * 32 + quad * 8);
  f32x4 o[2][4] = {};
  float lpart[2][4] = {};  // per-lane partial softmax denominators
  const int srk = t >> 3, sck = t & 7;
  const int gck = ((sck ^ (srk & 7)) * 8);  // swizzled global chunk (shorts)
  const int xh = l15 & 7;
  const int ktmax = 2 * qt + 1;
  for (int kt = 0; kt <= ktmax; ++kt) {
    __syncthreads();
#pragma unroll
    for (int i = 0; i < 2; ++i) {
      gl_lds16(kg + (size_t)(kt * 64 + srk + i * 32) * 64 + gck,
               &Ks[(srk + i * 32) * 64 + sck * 8]);
      gl_lds16(vg + (size_t)(srk + i * 32) * S_LEN + kt * 64 + gck,
               &Vts[(srk + i * 32) * 64 + sck * 8]);
    }
    __syncthreads();
    // S = q.k/8 - 8 (shift folded into accumulator init)
    f32x4 sacc[2][4];
#pragma unroll
    for (int mi = 0; mi < 2; ++mi)
#pragma unroll
      for (int nt = 0; nt < 4; ++nt) sacc[mi][nt] = (f32x4){-8.f, -8.f, -8.f, -8.f};
#pragma unroll
    for (int nt = 0; nt < 4; ++nt) {
      bf16x8 b0 = *reinterpret_cast<const bf16x8*>(
          &Ks[(nt * 16 + l15) * 64 + ((quad ^ xh) * 8)]);
      bf16x8 b1 = *reinterpret_cast<const bf16x8*>(
          &Ks[(nt * 16 + l15) * 64 + (((4 + quad) ^ xh) * 8)]);
#pragma unroll
      for (int mi = 0; mi < 2; ++mi) {
        sacc[mi][nt] = mfma16(aq[mi][0], b0, sacc[mi][nt]);
        sacc[mi][nt] = mfma16(aq[mi][1], b1, sacc[mi][nt]);
      }
    }
    if (kt >= 2 * qt) {  // diagonal tiles: causal mask
#pragma unroll
      for (int mi = 0; mi < 2; ++mi)
#pragma unroll
        for (int nt = 0; nt < 4; ++nt)
#pragma unroll
          for (int rg = 0; rg < 4; ++rg) {
            const int row = qt * 128 + w * 32 + mi * 16 + quad * 4 + rg;
            const int col = kt * 64 + nt * 16 + l15;
            if (col > row) sacc[mi][nt][rg] = -1e9f;
          }
    }
    // p = exp(s-8); accumulate per-lane l; write P to LDS (bf16, padded rows)
#pragma unroll
    for (int mi = 0; mi < 2; ++mi)
#pragma unroll
      for (int nt = 0; nt < 4; ++nt)
#pragma unroll
        for (int rg = 0; rg < 4; ++rg) {
          const float p = __expf(sacc[mi][nt][rg]);
          lpart[mi][rg] += p;
          Ps[(w * 32 + mi * 16 + quad * 4 + rg) * PS_STRIDE + nt * 16 + l15] = f2bf(p);
        }
    // PV: same-wave LDS round-trip (rows w*32..w*32+31 only, no barrier needed)
#pragma unroll
    for (int ks = 0; ks < 2; ++ks) {
      bf16x8 ap[2];
#pragma unroll
      for (int mi = 0; mi < 2; ++mi) {
        const unsigned short* pp =
            &Ps[(w * 32 + mi * 16 + l15) * PS_STRIDE + ks * 32 + quad * 8];
        bf16x4 lo = *reinterpret_cast<const bf16x4*>(pp);
        bf16x4 hi = *reinterpret_cast<const bf16x4*>(pp + 4);
        ap[mi] = __builtin_shufflevector(lo, hi, 0, 1, 2, 3, 4, 5, 6, 7);
      }
#pragma unroll
      for (int vt = 0; vt < 4; ++vt) {
        bf16x8 bv = *reinterpret_cast<const bf16x8*>(
            &Vts[(vt * 16 + l15) * 64 + (((ks * 4 + quad) ^ xh) * 8)]);
#pragma unroll
        for (int mi = 0; mi < 2; ++mi) o[mi][vt] = mfma16(ap[mi], bv, o[mi][vt]);
      }
    }
  }
  // final denominator reduce across the 16 col-lanes of each row
  float linv[2][4];
#pragma unroll
  for (int mi = 0; mi < 2; ++mi)
#pragma unroll
    for (int rg = 0; rg < 4; ++rg) {
      float rs = lpart[mi][rg];
#pragma unroll
      for (int d = 1; d < 16; d <<= 1) rs += __shfl_xor(rs, d);
      linv[mi][rg] = 1.0f / rs;
    }
#pragma unroll
  for (int mi = 0; mi < 2; ++mi)
#pragma unroll
    for (int vt = 0; vt < 4; ++vt)
#pragma unroll
      for (int rg = 0; rg < 4; ++rg) {
        const int row = w * 32 + mi * 16 + quad * 4 + rg;
        const int s = qt * 128 + row;
        const float ov = o[mi][vt][rg] * linv[mi][rg];
        attn[((size_t)(b * S_LEN + s)) * E_DIM + hh * 64 + vt * 16 + l15] = f2bf(ov);
      }
}

// ---------------- rmsnorm: h = x * rsqrt(mean(x^2)+eps) * w  (bf16 out) ----------------
__global__ __launch_bounds__(256) void rmsnorm_kernel(
    const float* __restrict__ x, const float* __restrict__ wgt,
    unsigned short* __restrict__ hout) {
  const int row = blockIdx.x;
  const int t = threadIdx.x;
  const float4 v = reinterpret_cast<const float4*>(x + (size_t)row * E_DIM)[t];
  float ss = v.x * v.x + v.y * v.y + v.z * v.z + v.w * v.w;
#pragma unroll
  for (int d = 1; d < 64; d <<= 1) ss += __shfl_xor(ss, d);
  __shared__ float red[4];
  if ((t & 63) == 0) red[t >> 6] = ss;
  __syncthreads();
  const float tot = red[0] + red[1] + red[2] + red[3];
  const float sc = rsqrtf(tot * (1.f / 1024.f) + 1.1920929e-07f);
  const float4 g = reinterpret_cast<const float4*>(wgt)[t];
  ushort4 ov;
  ov.x = f2bf(v.x * sc * g.x);
  ov.y = f2bf(v.y * sc * g.y);
  ov.z = f2bf(v.z * sc * g.z);
  ov.w = f2bf(v.w * sc * g.w);
  reinterpret_cast<ushort4*>(hout + (size_t)row * E_DIM)[t] = ov;
}

// ---------------- host ----------------
extern "C" void kernel_launch(void* const* d_in, const int* in_sizes, int n_in,
                              void* d_out, int out_size, void* d_ws, size_t ws_size,
                              hipStream_t stream) {
  (void)in_sizes; (void)n_in; (void)out_size; (void)ws_size;
  const float* emb = (const float*)d_in[0];
  const float* cosb = (const float*)d_in[2];
  const float* sinb = (const float*)d_in[3];
  const float* wq = (const float*)d_in[4];
  const float* wk = (const float*)d_in[5];
  const float* wv = (const float*)d_in[6];
  const float* wproj = (const float*)d_in[7];
  const float* mlpw = (const float*)d_in[9];
  const float* wup = (const float*)d_in[10];
  const float* wgate = (const float*)d_in[11];
  const float* wdown = (const float*)d_in[12];
  float* out = (float*)d_out;
  char* ws = (char*)d_ws;
  // layout (bytes): weights 32MiB | shared67 (emb_bf16,q,k,vt | aliased later by g) | attn | x | h
  unsigned short* wqkv_t = (unsigned short*)(ws + 0);
  unsigned short* wproj_t = (unsigned short*)(ws + 6291456);
  unsigned short* wupgate_t = (unsigned short*)(ws + 8388608);  // interleave-32 U/G, 8192x1024
  unsigned short* wdown_t = (unsigned short*)(ws + 25165824);
  unsigned short* embb = (unsigned short*)(ws + 33554432);
  unsigned short* qbuf = (unsigned short*)(ws + 50331648);
  unsigned short* kbuf = (unsigned short*)(ws + 67108864);
  unsigned short* vtbuf = (unsigned short*)(ws + 83886080);
  unsigned short* gbuf = (unsigned short*)(ws + 33554432);  // aliases embb..vtbuf (dead by then)
  unsigned short* attnb = (unsigned short*)(ws + 100663296);
  float* xbuf = (float*)(ws + 117440512);
  unsigned short* hbuf = (unsigned short*)(ws + 150994944);

  dim3 blk(256);
  // prep: casts + transposes to B^T layouts
  cast_emb_kernel<<<8192, blk, 0, stream>>>((const float4*)emb, (ushort4*)embb);
  transpose_cast_qkv<<<dim3(2, 32, 48), blk, 0, stream>>>(wq, wk, wv, wqkv_t);
  transpose_cast_kernel<<<dim3(32, 32, 1), blk, 0, stream>>>(wproj, wproj_t, 1024, 1024);
  transpose_cast_upgate<<<dim3(128, 32, 2), blk, 0, stream>>>(wup, wgate, wupgate_t);
  transpose_cast_kernel<<<dim3(32, 128, 1), blk, 0, stream>>>(wdown, wdown_t, 4096, 1024);
  // QKV + RoPE (q pre-scaled by 1/8): 256^2 4-phase pipelined, XCD-chunked
  gemm256<0><<<dim3(12, 32), dim3(512), 0, stream>>>(
      embb, wqkv_t, cosb, sinb, qbuf, kbuf, vtbuf, nullptr);
  // causal flash attention (LPT order)
  flash_attn<<<dim3(64, 16), blk, 0, stream>>>(qbuf, kbuf, vtbuf, attnb);
  // proj + residual -> x (fp32)
  gemm_bt<1, 1024><<<dim3(8, 64), blk, 0, stream>>>(attnb, wproj_t, emb, xbuf);
  // rmsnorm -> h (bf16)
  rmsnorm_kernel<<<8192, blk, 0, stream>>>(xbuf, mlpw, hbuf);
  // fused up/gate (interleave-32 B, 256^2 4-phase pipelined, mfma32) -> g (bf16)
  gemm256<3><<<dim3(32, 32), dim3(512), 0, stream>>>(
      hbuf, wupgate_t, nullptr, nullptr, nullptr, nullptr, nullptr, gbuf);
  // down + residual -> out (fp32): 256x128 triple-buffered pipeline, 1 block/CU
  gemm_down<<<dim3(8, 32), blk, 0, stream>>>(gbuf, wdown_t, xbuf, out);
}